// Round 7
// baseline (364.324 us; speedup 1.0000x reference)
//
#include <hip/hip_runtime.h>
#include <hip/hip_cooperative_groups.h>
#include <math.h>

namespace cg = cooperative_groups;

// ---------------------------------------------------------------------------
// SimpleSelfAttention  B=4 S=2048 D=1024  fp32
// Round 15: single persistent cooperative kernel. R14 measured a ~65-75us
// gap between the sum of kernel durations (~190) and wall time (260.8) —
// launch/drain overhead of 4 sequential graph nodes. Fuse prep/qkv/scores/pv
// into ONE dispatch with cg::grid().sync() between phases. 256 blocks x 512
// thr, 144 KiB LDS (1 block/CU, all co-resident). Core + epilogues are
// byte-identical to R14 (absmax-validated).
// ---------------------------------------------------------------------------

typedef _Float16 f16;
typedef _Float16 f16x8 __attribute__((ext_vector_type(8)));
typedef _Float16 f16x4 __attribute__((ext_vector_type(4)));
typedef float f32x4 __attribute__((ext_vector_type(4)));

__device__ __forceinline__ void glds16(const void* g, const void* l) {
    __builtin_amdgcn_global_load_lds(
        (const __attribute__((address_space(1))) void*)g,
        (__attribute__((address_space(3))) void*)l, 16, 0, 0);
}

#define VMCNT(n)  asm volatile("s_waitcnt vmcnt(" #n ")" ::: "memory")
#define LGKM(n)   asm volatile("s_waitcnt lgkmcnt(" #n ")" ::: "memory")
#define BARRIER() asm volatile("s_barrier" ::: "memory")
#define SCHEDB()  __builtin_amdgcn_sched_barrier(0)

// ---------------------------------------------------------------------------
// 256x128 NT fp16 MFMA core, BK=64, 3-deep LDS pipeline, counted vmcnt.
// (R9/R14 core, best measured). LDS: 3 x (A 256x64 + B 128x64) = 144 KiB,
// XOR-swizzled 16B slots -> 0 bank conflicts.
// ---------------------------------------------------------------------------
#define ABUF 16384      // f16 per A buffer (256*64)
#define BBUF 8192       // f16 per B buffer (128*64)
#define BOFF 49152      // f16 offset of B buffers (3*ABUF)

__device__ __forceinline__ void mfma_core3(
    const f16* A, int lda,
    const f16* B, int ldb,
    int K, int m0, int n0, f16* sm, f32x4 acc[4][4])
{
    const int tid  = threadIdx.x;
    const int lane = tid & 63;
    const int w    = tid >> 6;          // 0..7
    const int wr   = w >> 1;            // 0..3 : wave row (64 rows each)
    const int wc   = w & 1;             // 0..1 : wave col (64 cols each)
    const int lr   = lane & 15;
    const int kq   = lane >> 4;

    // staging lanes: 64 lanes cover 8 rows x 8 slots of 16B
    const int rl = lane >> 3;           // row within 8-row group
    const int ch = (lane & 7) ^ rl;     // source k-chunk for this slot

    const f16* gA[4];
    #pragma unroll
    for (int p = 0; p < 4; ++p)
        gA[p] = A + (size_t)(m0 + p * 64 + w * 8 + rl) * lda + ch * 8;
    const f16* gB[2];
    #pragma unroll
    for (int p = 0; p < 2; ++p)
        gB[p] = B + (size_t)(n0 + p * 64 + w * 8 + rl) * ldb + ch * 8;

    const int NT = K >> 6;

    f16* sA0 = sm;             f16* sB0 = sm + BOFF;
    f16* sA1 = sm + ABUF;      f16* sB1 = sm + BOFF + BBUF;
    f16* sA2 = sm + 2 * ABUF;  f16* sB2 = sm + BOFF + 2 * BBUF;

    #define STAGE(kofs, dA, dB) do {                                          \
        _Pragma("unroll")                                                     \
        for (int p = 0; p < 4; ++p)                                           \
            glds16(gA[p] + (kofs), (dA) + w * 512 + p * 4096);                \
        _Pragma("unroll")                                                     \
        for (int p = 0; p < 2; ++p)                                           \
            glds16(gB[p] + (kofs), (dB) + w * 512 + p * 4096);                \
    } while (0)

    // prologue: stage tiles 0,1 (12 loads in flight)
    STAGE(0,  sA0, sB0);
    STAGE(64, sA1, sB1);

    int kst = 128;
    f16* curA = sA0; f16* curB = sB0;
    f16* nxtA = sA1; f16* nxtB = sB1;
    f16* farA = sA2; f16* farB = sB2;

    for (int t = 0; t < NT; ++t) {
        if (t + 2 < NT) {               // issue tile t+2 (uniform branch)
            STAGE(kst, farA, farB);
            kst += 64;
            VMCNT(12);                  // certify tile t (12 newer in flight)
        } else if (t + 1 < NT) {
            VMCNT(6);
        } else {
            VMCNT(0);
        }
        BARRIER();

        #pragma unroll
        for (int kk = 0; kk < 2; ++kk) {
            f16x8 a[4], b[4];
            const int c = kk * 4 + kq;
            #pragma unroll
            for (int i = 0; i < 4; ++i) {
                const int ra = wr * 64 + i * 16 + lr;
                a[i] = *(const f16x8*)&curA[ra * 64 + ((c ^ (ra & 7)) * 8)];
            }
            #pragma unroll
            for (int j = 0; j < 4; ++j) {
                const int rb = wc * 64 + j * 16 + lr;
                b[j] = *(const f16x8*)&curB[rb * 64 + ((c ^ (rb & 7)) * 8)];
            }
            LGKM(0);
            SCHEDB();
            __builtin_amdgcn_s_setprio(1);
            #pragma unroll
            for (int i = 0; i < 4; ++i)
                #pragma unroll
                for (int j = 0; j < 4; ++j)
                    acc[i][j] = __builtin_amdgcn_mfma_f32_16x16x32_f16(a[i], b[j], acc[i][j], 0, 0, 0);
            __builtin_amdgcn_s_setprio(0);
            BARRIER();
        }

        f16* tA = curA; f16* tB = curB;
        curA = nxtA; curB = nxtB;
        nxtA = farA; nxtB = farB;
        farA = tA;   farB = tB;
    }
    #undef STAGE
}

// ---------------------------------------------------------------------------
// Persistent fused kernel: prep -> qkv -> scores -> pv, grid syncs between.
// xh/Wh3/P intentionally NOT __restrict__ (P aliases the xh/Wh3 region).
// ---------------------------------------------------------------------------
__global__ __launch_bounds__(512) void fused_attn_kernel(
    const float* __restrict__ x,
    const float* __restrict__ Wq, const float* __restrict__ Wk,
    const float* __restrict__ Wv,
    const float* __restrict__ bq, const float* __restrict__ bk,
    const float* __restrict__ bv,
    f16* xh, f16* Wh3, f16* P,
    f16* __restrict__ Qh, f16* __restrict__ Kh, f16* __restrict__ Vt,
    float* __restrict__ sums, float* __restrict__ out)
{
    extern __shared__ __align__(16) f16 smem[];
    cg::grid_group grid = cg::this_grid();

    const int bid  = blockIdx.x;        // 0..255
    const int tid  = threadIdx.x;       // 0..511
    const int lane = tid & 63;
    const int w    = tid >> 6;
    const int wm   = (w >> 1) * 64;
    const int wn   = (w & 1) * 64;
    const int col  = lane & 15;
    const int quad = lane >> 4;

    // ===== phase 0: prep (fp32->fp16 x + W planes, zero sums) =====
    {
        const int gt = bid * 512 + tid;             // 0..131071
        if (gt < 2048) {
            float4 z = {0.f, 0.f, 0.f, 0.f};
            ((float4*)sums)[gt] = z;                // 8192 floats
        }
        #pragma unroll 2
        for (int k = 0; k < 16; ++k) {              // 2,097,152 float4 exact
            const int i = k * 131072 + gt;
            float4 v = ((const float4*)x)[i];
            f16x4 h = { (f16)v.x, (f16)v.y, (f16)v.z, (f16)v.w };
            ((f16x4*)xh)[i] = h;
        }
        #pragma unroll
        for (int p = 0; p < 3; ++p) {               // 262,144 float4 / plane
            const float* src = (p == 0) ? Wq : (p == 1) ? Wk : Wv;
            f16* dst = Wh3 + (size_t)p * 1048576;
            #pragma unroll
            for (int k = 0; k < 2; ++k) {
                const int i = k * 131072 + gt;
                float4 v = ((const float4*)src)[i];
                f16x4 h = { (f16)v.x, (f16)v.y, (f16)v.z, (f16)v.w };
                ((f16x4*)dst)[i] = h;
            }
        }
    }
    grid.sync();

    // ===== phase 1: qkv (3 tiles/block; XCD swizzle over 768 tiles) =====
    for (int rr = 0; rr < 3; ++rr) {
        const int t = bid + rr * 256;
        const int flat = (t & 7) * 96 + (t >> 3);
        const int bx = flat & 7;
        const int by = (flat >> 3) & 31;
        const int bz = flat >> 8;
        const int m0 = by * 256;
        const int n0 = bx * 128;

        f32x4 acc[4][4];
        #pragma unroll
        for (int i = 0; i < 4; ++i)
            #pragma unroll
            for (int j = 0; j < 4; ++j) acc[i][j] = (f32x4){0.f, 0.f, 0.f, 0.f};

        mfma_core3(xh, 1024, Wh3 + (size_t)bz * 1048576, 1024, 1024, m0, n0, smem, acc);

        if (bz == 2) {
            // V stored transposed: lane holds 4 consecutive s for one d.
            #pragma unroll
            for (int i = 0; i < 4; ++i) {
                const int gmb = m0 + wm + i * 16 + quad * 4;   // r=0 base (s)
                const int bb_ = gmb >> 11;
                const int s   = gmb & 2047;
                f16* vtb = Vt + (size_t)bb_ * 1024 * 2048;
                #pragma unroll
                for (int j = 0; j < 4; ++j) {
                    const int gn = n0 + wn + j * 16 + col;
                    const float bbv = bv[gn];
                    f16x4 v = { (f16)(acc[i][j][0] + bbv), (f16)(acc[i][j][1] + bbv),
                                (f16)(acc[i][j][2] + bbv), (f16)(acc[i][j][3] + bbv) };
                    *(f16x4*)&vtb[(size_t)gn * 2048 + s] = v;
                }
            }
        } else {
            const float* bias = (bz == 0) ? bq : bk;
            const float  sc   = (bz == 0) ? 0.03125f : 1.0f;  // fold 1/sqrt(D) into Q
            f16* C = (bz == 0) ? Qh : Kh;
            #pragma unroll
            for (int j = 0; j < 4; ++j) {
                const int gn = n0 + wn + j * 16 + col;
                const float bb = bias[gn];
                #pragma unroll
                for (int i = 0; i < 4; ++i)
                    #pragma unroll
                    for (int r = 0; r < 4; ++r) {
                        const int gm = m0 + wm + i * 16 + quad * 4 + r;
                        C[(size_t)gm * 1024 + gn] = (f16)((acc[i][j][r] + bb) * sc);
                    }
            }
        }
    }
    grid.sync();

    // ===== phase 2: scores (2 tiles/block over 512 tiles) =====
    for (int rr = 0; rr < 2; ++rr) {
        const int t = bid + rr * 256;
        const int bx = t & 15;
        const int by = (t >> 4) & 7;
        const int b  = t >> 7;
        const int m0 = by * 256;
        const int n0 = bx * 128;

        f32x4 acc[4][4];
        #pragma unroll
        for (int i = 0; i < 4; ++i)
            #pragma unroll
            for (int j = 0; j < 4; ++j) acc[i][j] = (f32x4){0.f, 0.f, 0.f, 0.f};

        const size_t ao = (size_t)b * 2048 * 1024;
        mfma_core3(Qh + ao, 1024, Kh + ao, 1024, 1024, m0, n0, smem, acc);

        f16* C = P + (size_t)b * 2048 * 2048;
        float rp[4][4];
        #pragma unroll
        for (int i = 0; i < 4; ++i)
            #pragma unroll
            for (int r = 0; r < 4; ++r) rp[i][r] = 0.0f;

        #pragma unroll
        for (int i = 0; i < 4; ++i)
            #pragma unroll
            for (int r = 0; r < 4; ++r) {
                const int gm = m0 + wm + i * 16 + quad * 4 + r;
                #pragma unroll
                for (int j = 0; j < 4; ++j) {
                    const int gn = n0 + wn + j * 16 + col;
                    const f16 p = (f16)__expf(acc[i][j][r]);
                    C[(size_t)gm * 2048 + gn] = p;
                    rp[i][r] += (float)p;   // sum what pv will actually read
                }
            }

        #pragma unroll
        for (int i = 0; i < 4; ++i)
            #pragma unroll
            for (int r = 0; r < 4; ++r) {
                float v = rp[i][r];
                v += __shfl_xor(v, 1);
                v += __shfl_xor(v, 2);
                v += __shfl_xor(v, 4);
                v += __shfl_xor(v, 8);
                rp[i][r] = v;
            }
        if (col == 0) {
            #pragma unroll
            for (int i = 0; i < 4; ++i)
                #pragma unroll
                for (int r = 0; r < 4; ++r) {
                    const int row = m0 + wm + i * 16 + quad * 4 + r;
                    atomicAdd(&sums[b * 2048 + row], rp[i][r]);
                }
        }
    }
    grid.sync();

    // ===== phase 3: pv (1 tile/block over 256 tiles) =====
    {
        const int t  = bid;
        const int bx = t & 7;
        const int by = (t >> 3) & 7;
        const int b  = t >> 6;
        const int m0 = by * 256;
        const int n0 = bx * 128;

        f32x4 acc[4][4];
        #pragma unroll
        for (int i = 0; i < 4; ++i)
            #pragma unroll
            for (int j = 0; j < 4; ++j) acc[i][j] = (f32x4){0.f, 0.f, 0.f, 0.f};

        const size_t ao = (size_t)b * 2048 * 2048;
        const size_t bo = (size_t)b * 1024 * 2048;
        mfma_core3(P + ao, 2048, Vt + bo, 2048, 2048, m0, n0, smem, acc);

        float* C = out + (size_t)b * 2048 * 1024;
        #pragma unroll
        for (int i = 0; i < 4; ++i)
            #pragma unroll
            for (int r = 0; r < 4; ++r) {
                const int rl = m0 + wm + i * 16 + quad * 4 + r;
                const float inv = 1.0f / sums[b * 2048 + rl];
                #pragma unroll
                for (int j = 0; j < 4; ++j) {
                    const int gn = n0 + wn + j * 16 + col;
                    C[(size_t)rl * 1024 + gn] = acc[i][j][r] * inv;
                }
            }
    }
}

// ===========================================================================
extern "C" void kernel_launch(void* const* d_in, const int* in_sizes, int n_in,
                              void* d_out, int out_size, void* d_ws, size_t ws_size,
                              hipStream_t stream)
{
    (void)in_sizes; (void)n_in; (void)out_size; (void)ws_size;
    const float* x  = (const float*)d_in[0];
    const float* Wq = (const float*)d_in[1];
    const float* bq = (const float*)d_in[2];
    const float* Wk = (const float*)d_in[3];
    const float* bk = (const float*)d_in[4];
    const float* Wv = (const float*)d_in[5];
    const float* bv = (const float*)d_in[6];
    float* out = (float*)d_out;

    const size_t MB = 1024 * 1024;
    char* w = (char*)d_ws;
    // [0..16)  xh   — dead after qkv   \
    // [16..22) Wh3  — dead after qkv    > P (32 MiB) aliases [0..38)
    // [22..38) (free)                  /
    // [38..54) Qh   [54..70) Kh   [70..86) Vt   [86..87) sums
    f16*   xh   = (f16*)(w + 0 * MB);
    f16*   Wh3  = (f16*)(w + 16 * MB);
    f16*   Qh   = (f16*)(w + 38 * MB);
    f16*   Kh   = (f16*)(w + 54 * MB);
    f16*   Vt   = (f16*)(w + 70 * MB);
    float* sums = (float*)(w + 86 * MB);
    f16*   P    = (f16*)(w + 0 * MB);

    static bool attr_set = false;
    if (!attr_set) {
        (void)hipFuncSetAttribute(reinterpret_cast<const void*>(fused_attn_kernel),
                            hipFuncAttributeMaxDynamicSharedMemorySize, 147456);
        attr_set = true;
    }

    void* args[] = {
        (void*)&x, (void*)&Wq, (void*)&Wk, (void*)&Wv,
        (void*)&bq, (void*)&bk, (void*)&bv,
        (void*)&xh, (void*)&Wh3, (void*)&P,
        (void*)&Qh, (void*)&Kh, (void*)&Vt,
        (void*)&sums, (void*)&out
    };
    (void)hipLaunchCooperativeKernel(
        reinterpret_cast<void*>(fused_attn_kernel),
        dim3(256), dim3(512), args, 147456, stream);
}

// Round 8
// 247.361 us; speedup vs baseline: 1.4728x; 1.4728x over previous
//
#include <hip/hip_runtime.h>
#include <math.h>

// ---------------------------------------------------------------------------
// SimpleSelfAttention  B=4 S=2048 D=1024  fp32
// Round 16: revert R15 fusion (grid.sync kills L2 reuse; fixed ~90us harness
// overhead regardless of launch count). R14 structure +:
//  - scores: NEW 256x256 core (8 waves, wave tile 128x64, 2-deep dbuf,
//    counted vmcnt(8)) — 25% less LDS traffic/FLOP, exactly 1 round (256 wg).
//  - mfma_core3: 3 -> 2 barriers/K-tile; end-of-tile barrier moved before
//    kk1 MFMAs (after lgkmcnt(0)) so next staging overlaps the MFMA tail.
// ---------------------------------------------------------------------------

typedef _Float16 f16;
typedef _Float16 f16x8 __attribute__((ext_vector_type(8)));
typedef _Float16 f16x4 __attribute__((ext_vector_type(4)));
typedef float f32x4 __attribute__((ext_vector_type(4)));

__device__ __forceinline__ void glds16(const void* g, const void* l) {
    __builtin_amdgcn_global_load_lds(
        (const __attribute__((address_space(1))) void*)g,
        (__attribute__((address_space(3))) void*)l, 16, 0, 0);
}

#define VMCNT(n)  asm volatile("s_waitcnt vmcnt(" #n ")" ::: "memory")
#define LGKM(n)   asm volatile("s_waitcnt lgkmcnt(" #n ")" ::: "memory")
#define BARRIER() asm volatile("s_barrier" ::: "memory")
#define SCHEDB()  __builtin_amdgcn_sched_barrier(0)

// fused prep: fp32->fp16 for x (blocks [0,8192)), W planes (blocks [8192,11264)),
// zero sums (blocks [0,8))
__global__ __launch_bounds__(256) void prep_kernel(
    const float* __restrict__ x,
    const float* __restrict__ Wq, const float* __restrict__ Wk,
    const float* __restrict__ Wv,
    f16* __restrict__ xh, f16* __restrict__ Wh3, float* __restrict__ sums)
{
    const int bid = blockIdx.x, tid = threadIdx.x;
    if (bid < 8) {
        float4 z = {0.f, 0.f, 0.f, 0.f};
        ((float4*)sums)[bid * 256 + tid] = z;     // 8*256*4 = 8192 floats
    }
    if (bid < 8192) {
        const int i = bid * 256 + tid;
        float4 v = ((const float4*)x)[i];
        f16x4 h = { (f16)v.x, (f16)v.y, (f16)v.z, (f16)v.w };
        ((f16x4*)xh)[i] = h;
    } else {
        const int wid   = bid - 8192;             // 0..3071
        const int plane = wid >> 10;              // 0..2
        const int i     = (wid & 1023) * 256 + tid;
        const float* src = (plane == 0) ? Wq : (plane == 1) ? Wk : Wv;
        float4 v = ((const float4*)src)[i];
        f16x4 h = { (f16)v.x, (f16)v.y, (f16)v.z, (f16)v.w };
        ((f16x4*)(Wh3 + (size_t)plane * 1024 * 1024))[i] = h;
    }
}

// ---------------------------------------------------------------------------
// 256x128 NT fp16 MFMA core, BK=64, 3-deep LDS pipeline, counted vmcnt.
// 512 thr = 8 waves (4M x 2N), wave tile 64x64. LDS 144 KiB, XOR-swizzled.
// 2 barriers/K-tile: entry barrier after vmcnt; exit barrier after kk1's
// lgkmcnt(0) (reads retired) but BEFORE kk1 MFMAs -> staging overlaps tail.
// ---------------------------------------------------------------------------
#define ABUF 16384      // f16 per A buffer (256*64)
#define BBUF 8192       // f16 per B buffer (128*64)
#define BOFF 49152      // f16 offset of B buffers (3*ABUF)

__device__ __forceinline__ void mfma_core3(
    const f16* A, int lda,
    const f16* B, int ldb,
    int K, int m0, int n0, f16* sm, f32x4 acc[4][4])
{
    const int tid  = threadIdx.x;
    const int lane = tid & 63;
    const int w    = tid >> 6;          // 0..7
    const int wr   = w >> 1;            // 0..3 : wave row (64 rows each)
    const int wc   = w & 1;             // 0..1 : wave col (64 cols each)
    const int lr   = lane & 15;
    const int kq   = lane >> 4;

    const int rl = lane >> 3;           // staging row within 8-row group
    const int ch = (lane & 7) ^ rl;     // source k-chunk for this slot

    const f16* gA[4];
    #pragma unroll
    for (int p = 0; p < 4; ++p)
        gA[p] = A + (size_t)(m0 + p * 64 + w * 8 + rl) * lda + ch * 8;
    const f16* gB[2];
    #pragma unroll
    for (int p = 0; p < 2; ++p)
        gB[p] = B + (size_t)(n0 + p * 64 + w * 8 + rl) * ldb + ch * 8;

    const int NT = K >> 6;

    f16* sA0 = sm;             f16* sB0 = sm + BOFF;
    f16* sA1 = sm + ABUF;      f16* sB1 = sm + BOFF + BBUF;
    f16* sA2 = sm + 2 * ABUF;  f16* sB2 = sm + BOFF + 2 * BBUF;

    #define STAGE(kofs, dA, dB) do {                                          \
        _Pragma("unroll")                                                     \
        for (int p = 0; p < 4; ++p)                                           \
            glds16(gA[p] + (kofs), (dA) + w * 512 + p * 4096);                \
        _Pragma("unroll")                                                     \
        for (int p = 0; p < 2; ++p)                                           \
            glds16(gB[p] + (kofs), (dB) + w * 512 + p * 4096);                \
    } while (0)

    // prologue: stage tiles 0,1 (12 loads in flight)
    STAGE(0,  sA0, sB0);
    STAGE(64, sA1, sB1);

    int kst = 128;
    f16* curA = sA0; f16* curB = sB0;
    f16* nxtA = sA1; f16* nxtB = sB1;
    f16* farA = sA2; f16* farB = sB2;

    for (int t = 0; t < NT; ++t) {
        if (t + 2 < NT) {               // issue tile t+2 (uniform branch)
            STAGE(kst, farA, farB);
            kst += 64;
            VMCNT(12);                  // certify tile t (12 newer in flight)
        } else if (t + 1 < NT) {
            VMCNT(6);
        } else {
            VMCNT(0);
        }
        BARRIER();                      // tile t collectively ready

        // kk = 0
        {
            f16x8 a[4], b[4];
            #pragma unroll
            for (int i = 0; i < 4; ++i) {
                const int ra = wr * 64 + i * 16 + lr;
                a[i] = *(const f16x8*)&curA[ra * 64 + ((kq ^ (ra & 7)) * 8)];
            }
            #pragma unroll
            for (int j = 0; j < 4; ++j) {
                const int rb = wc * 64 + j * 16 + lr;
                b[j] = *(const f16x8*)&curB[rb * 64 + ((kq ^ (rb & 7)) * 8)];
            }
            LGKM(0);
            SCHEDB();
            __builtin_amdgcn_s_setprio(1);
            #pragma unroll
            for (int i = 0; i < 4; ++i)
                #pragma unroll
                for (int j = 0; j < 4; ++j)
                    acc[i][j] = __builtin_amdgcn_mfma_f32_16x16x32_f16(a[i], b[j], acc[i][j], 0, 0, 0);
            __builtin_amdgcn_s_setprio(0);
        }
        // kk = 1 : barrier after reads retire, before MFMAs
        {
            f16x8 a[4], b[4];
            const int c = 4 + kq;
            #pragma unroll
            for (int i = 0; i < 4; ++i) {
                const int ra = wr * 64 + i * 16 + lr;
                a[i] = *(const f16x8*)&curA[ra * 64 + ((c ^ (ra & 7)) * 8)];
            }
            #pragma unroll
            for (int j = 0; j < 4; ++j) {
                const int rb = wc * 64 + j * 16 + lr;
                b[j] = *(const f16x8*)&curB[rb * 64 + ((c ^ (rb & 7)) * 8)];
            }
            LGKM(0);                    // all my reads of cur retired
            BARRIER();                  // collective: cur reusable next iter
            SCHEDB();
            __builtin_amdgcn_s_setprio(1);
            #pragma unroll
            for (int i = 0; i < 4; ++i)
                #pragma unroll
                for (int j = 0; j < 4; ++j)
                    acc[i][j] = __builtin_amdgcn_mfma_f32_16x16x32_f16(a[i], b[j], acc[i][j], 0, 0, 0);
            __builtin_amdgcn_s_setprio(0);
        }

        f16* tA = curA; f16* tB = curB;
        curA = nxtA; curB = nxtB;
        nxtA = farA; nxtB = farB;
        farA = tA;   farB = tB;
    }
    #undef STAGE
}

// ---------------------------------------------------------------------------
// 256x256 NT fp16 MFMA core (scores): 8 waves 2M x 4N, wave tile 128x64,
// BK=64, 2-deep double buffer, counted vmcnt(8). LDS 2x(32K A + 32K B)=128KiB.
// 25% less DS traffic per FLOP than the 256x128 core.
// ---------------------------------------------------------------------------
__device__ __forceinline__ void mfma_core8w(
    const f16* A, int lda,
    const f16* B, int ldb,
    int K, int m0, int n0, f16* sm, f32x4 (&acc)[8][4])
{
    const int tid  = threadIdx.x;
    const int lane = tid & 63;
    const int w    = tid >> 6;          // 0..7
    const int wr   = w >> 2;            // 0..1 : 128-row half
    const int wn   = w & 3;             // 0..3 : 64-col quarter
    const int lr   = lane & 15;
    const int kq   = lane >> 4;

    const int rl = lane >> 3;
    const int ch = (lane & 7) ^ rl;

    const f16* gA[4];
    #pragma unroll
    for (int p = 0; p < 4; ++p)
        gA[p] = A + (size_t)(m0 + p * 64 + w * 8 + rl) * lda + ch * 8;
    const f16* gB[4];
    #pragma unroll
    for (int p = 0; p < 4; ++p)
        gB[p] = B + (size_t)(n0 + p * 64 + w * 8 + rl) * ldb + ch * 8;

    const int NT = K >> 6;

    f16* sA0 = sm;              f16* sA1 = sm + 16384;
    f16* sB0 = sm + 32768;      f16* sB1 = sm + 49152;

    #define STAGE8(kofs, dA, dB) do {                                         \
        _Pragma("unroll")                                                     \
        for (int p = 0; p < 4; ++p)                                           \
            glds16(gA[p] + (kofs), (dA) + w * 512 + p * 4096);                \
        _Pragma("unroll")                                                     \
        for (int p = 0; p < 4; ++p)                                           \
            glds16(gB[p] + (kofs), (dB) + w * 512 + p * 4096);                \
    } while (0)

    STAGE8(0, sA0, sB0);                // tile 0 -> buf0 (8 loads)

    f16* curA = sA0; f16* curB = sB0;
    f16* othA = sA1; f16* othB = sB1;

    for (int t = 0; t < NT; ++t) {
        if (t + 1 < NT) {               // stage tile t+1 into other buffer
            STAGE8((t + 1) * 64, othA, othB);
            VMCNT(8);                   // certify tile t (8 newer in flight)
        } else {
            VMCNT(0);
        }
        BARRIER();                      // tile t collectively ready

        #pragma unroll
        for (int kk = 0; kk < 2; ++kk) {
            f16x8 a[8], b[4];
            const int c = kk * 4 + kq;
            #pragma unroll
            for (int i = 0; i < 8; ++i) {
                const int ra = wr * 128 + i * 16 + lr;
                a[i] = *(const f16x8*)&curA[ra * 64 + ((c ^ (ra & 7)) * 8)];
            }
            #pragma unroll
            for (int j = 0; j < 4; ++j) {
                const int rb = wn * 64 + j * 16 + lr;
                b[j] = *(const f16x8*)&curB[rb * 64 + ((c ^ (rb & 7)) * 8)];
            }
            LGKM(0);
            if (kk == 1) BARRIER();     // all reads of cur retired -> reusable
            SCHEDB();
            __builtin_amdgcn_s_setprio(1);
            #pragma unroll
            for (int i = 0; i < 8; ++i)
                #pragma unroll
                for (int j = 0; j < 4; ++j)
                    acc[i][j] = __builtin_amdgcn_mfma_f32_16x16x32_f16(a[i], b[j], acc[i][j], 0, 0, 0);
            __builtin_amdgcn_s_setprio(0);
        }

        f16* x;
        x = curA; curA = othA; othA = x;
        x = curB; curB = othB; othB = x;
    }
    #undef STAGE8
}

// grid logical (8, 32, 3): z=0 Q (x 1/32), z=1 K, z=2 V (written transposed)
__global__ __launch_bounds__(512) void qkv_mfma_kernel(
    const f16* __restrict__ xh, const f16* __restrict__ Wh,  // [3][D*D]
    const float* __restrict__ bq, const float* __restrict__ bk,
    const float* __restrict__ bv,
    f16* __restrict__ Qh, f16* __restrict__ Kh, f16* __restrict__ Vt)
{
    extern __shared__ __align__(16) f16 smem[];
    // XCD swizzle: nwg=768, cpx=96
    int flat = blockIdx.x + 8 * (blockIdx.y + 32 * blockIdx.z);
    flat = (flat & 7) * 96 + (flat >> 3);
    const int bx = flat & 7;
    const int by = (flat >> 3) & 31;
    const int bz = flat >> 8;

    const int m0 = by * 256;
    const int n0 = bx * 128;

    f32x4 acc[4][4];
    #pragma unroll
    for (int i = 0; i < 4; ++i)
        #pragma unroll
        for (int j = 0; j < 4; ++j) acc[i][j] = (f32x4){0.f, 0.f, 0.f, 0.f};

    mfma_core3(xh, 1024, Wh + (size_t)bz * 1024 * 1024, 1024, 1024, m0, n0, smem, acc);

    const int lane = threadIdx.x & 63;
    const int w    = threadIdx.x >> 6;
    const int wm = (w >> 1) * 64;
    const int wn = (w & 1) * 64;
    const int col  = lane & 15;
    const int quad = lane >> 4;

    if (bz == 2) {
        // V stored transposed: lane holds 4 consecutive s for one d.
        #pragma unroll
        for (int i = 0; i < 4; ++i) {
            const int gmb = m0 + wm + i * 16 + quad * 4;   // r=0 base (s)
            const int bb_ = gmb >> 11;
            const int s   = gmb & 2047;
            f16* vtb = Vt + (size_t)bb_ * 1024 * 2048;
            #pragma unroll
            for (int j = 0; j < 4; ++j) {
                const int gn = n0 + wn + j * 16 + col;
                const float bbv = bv[gn];
                f16x4 v = { (f16)(acc[i][j][0] + bbv), (f16)(acc[i][j][1] + bbv),
                            (f16)(acc[i][j][2] + bbv), (f16)(acc[i][j][3] + bbv) };
                *(f16x4*)&vtb[(size_t)gn * 2048 + s] = v;
            }
        }
    } else {
        const float* bias = (bz == 0) ? bq : bk;
        const float  sc   = (bz == 0) ? 0.03125f : 1.0f;  // fold 1/sqrt(D) into Q
        f16* C = (bz == 0) ? Qh : Kh;
        #pragma unroll
        for (int j = 0; j < 4; ++j) {
            const int gn = n0 + wn + j * 16 + col;
            const float bb = bias[gn];
            #pragma unroll
            for (int i = 0; i < 4; ++i)
                #pragma unroll
                for (int r = 0; r < 4; ++r) {
                    const int gm = m0 + wm + i * 16 + quad * 4 + r;
                    C[(size_t)gm * 1024 + gn] = (f16)((acc[i][j][r] + bb) * sc);
                }
        }
    }
}

// grid (8, 8, 4): 256x256 tiles, exactly 1 round. P = exp(QK^T) fp16,
// row sums accumulated into sums[b*S + row] via atomicAdd.
__global__ __launch_bounds__(512, 2) void scores_exp_kernel(
    const f16* __restrict__ Qh, const f16* __restrict__ Kh,
    f16* __restrict__ P, float* __restrict__ sums)
{
    extern __shared__ __align__(16) f16 smem[];
    const int b  = blockIdx.z;
    const int m0 = blockIdx.y * 256;
    const int n0 = blockIdx.x * 256;

    f32x4 acc[8][4];
    #pragma unroll
    for (int i = 0; i < 8; ++i)
        #pragma unroll
        for (int j = 0; j < 4; ++j) acc[i][j] = (f32x4){0.f, 0.f, 0.f, 0.f};

    const size_t ao = (size_t)b * 2048 * 1024;
    mfma_core8w(Qh + ao, 1024, Kh + ao, 1024, 1024, m0, n0, smem, acc);

    const int lane = threadIdx.x & 63;
    const int w    = threadIdx.x >> 6;
    const int wr = w >> 2, wn = w & 3;
    const int col  = lane & 15;
    const int quad = lane >> 4;
    f16* C = P + (size_t)b * 2048 * 2048;

    float rp[8][4];
    #pragma unroll
    for (int i = 0; i < 8; ++i)
        #pragma unroll
        for (int r = 0; r < 4; ++r) rp[i][r] = 0.0f;

    #pragma unroll
    for (int i = 0; i < 8; ++i)
        #pragma unroll
        for (int r = 0; r < 4; ++r) {
            const int gm = m0 + wr * 128 + i * 16 + quad * 4 + r;
            #pragma unroll
            for (int j = 0; j < 4; ++j) {
                const int gn = n0 + wn * 64 + j * 16 + col;
                const f16 p = (f16)__expf(acc[i][j][r]);
                C[(size_t)gm * 2048 + gn] = p;
                rp[i][r] += (float)p;   // sum what pv will actually read
            }
        }

    #pragma unroll
    for (int i = 0; i < 8; ++i)
        #pragma unroll
        for (int r = 0; r < 4; ++r) {
            float v = rp[i][r];
            v += __shfl_xor(v, 1);
            v += __shfl_xor(v, 2);
            v += __shfl_xor(v, 4);
            v += __shfl_xor(v, 8);
            rp[i][r] = v;
        }
    if (col == 0) {
        #pragma unroll
        for (int i = 0; i < 8; ++i)
            #pragma unroll
            for (int r = 0; r < 4; ++r) {
                const int row = m0 + wr * 128 + i * 16 + quad * 4 + r;
                atomicAdd(&sums[b * 2048 + row], rp[i][r]);
            }
    }
}

// grid (8, 8, 4); out[r] = (P[r] @ Vt^T) / sums[r]
__global__ __launch_bounds__(512) void pv_mfma_kernel(
    const f16* __restrict__ P, const f16* __restrict__ Vt,
    const float* __restrict__ sums, float* __restrict__ out)
{
    extern __shared__ __align__(16) f16 smem[];
    const int b  = blockIdx.z;
    const int m0 = blockIdx.y * 256;
    const int n0 = blockIdx.x * 128;

    f32x4 acc[4][4];
    #pragma unroll
    for (int i = 0; i < 4; ++i)
        #pragma unroll
        for (int j = 0; j < 4; ++j) acc[i][j] = (f32x4){0.f, 0.f, 0.f, 0.f};

    const size_t ao = (size_t)b * 2048 * 2048;
    const size_t bo = (size_t)b * 1024 * 2048;
    mfma_core3(P + ao, 2048, Vt + bo, 2048, 2048, m0, n0, smem, acc);

    const int lane = threadIdx.x & 63;
    const int w    = threadIdx.x >> 6;
    const int wm = (w >> 1) * 64;
    const int wn = (w & 1) * 64;
    const int col  = lane & 15;
    const int quad = lane >> 4;
    float* C = out + (size_t)b * 2048 * 1024;

    #pragma unroll
    for (int i = 0; i < 4; ++i)
        #pragma unroll
        for (int r = 0; r < 4; ++r) {
            const int rl = m0 + wm + i * 16 + quad * 4 + r;
            const float inv = 1.0f / sums[b * 2048 + rl];
            #pragma unroll
            for (int j = 0; j < 4; ++j) {
                const int gn = n0 + wn + j * 16 + col;
                C[(size_t)rl * 1024 + gn] = acc[i][j][r] * inv;
            }
        }
}

// ===========================================================================
extern "C" void kernel_launch(void* const* d_in, const int* in_sizes, int n_in,
                              void* d_out, int out_size, void* d_ws, size_t ws_size,
                              hipStream_t stream)
{
    (void)in_sizes; (void)n_in; (void)out_size; (void)ws_size;
    const int Bn = 4, S = 2048, D = 1024;
    const float* x  = (const float*)d_in[0];
    const float* Wq = (const float*)d_in[1];
    const float* bq = (const float*)d_in[2];
    const float* Wk = (const float*)d_in[3];
    const float* bk = (const float*)d_in[4];
    const float* Wv = (const float*)d_in[5];
    const float* bv = (const float*)d_in[6];
    float* out = (float*)d_out;

    const size_t MB = 1024 * 1024;
    char* w = (char*)d_ws;
    // [0..16)  xh   — dead after qkv   \
    // [16..22) Wh3  — dead after qkv    > P (32 MiB) aliases [0..38)
    // [22..38) (free)                  /
    // [38..54) Qh   [54..70) Kh   [70..86) Vt   [86..87) sums
    f16*   xh   = (f16*)(w + 0 * MB);
    f16*   Wh3  = (f16*)(w + 16 * MB);
    f16*   Qh   = (f16*)(w + 38 * MB);
    f16*   Kh   = (f16*)(w + 54 * MB);
    f16*   Vt   = (f16*)(w + 70 * MB);
    float* sums = (float*)(w + 86 * MB);
    f16*   P    = (f16*)(w + 0 * MB);

    static bool attr_set = false;
    if (!attr_set) {
        (void)hipFuncSetAttribute(reinterpret_cast<const void*>(qkv_mfma_kernel),
                            hipFuncAttributeMaxDynamicSharedMemorySize, 147456);
        (void)hipFuncSetAttribute(reinterpret_cast<const void*>(scores_exp_kernel),
                            hipFuncAttributeMaxDynamicSharedMemorySize, 131072);
        (void)hipFuncSetAttribute(reinterpret_cast<const void*>(pv_mfma_kernel),
                            hipFuncAttributeMaxDynamicSharedMemorySize, 147456);
        attr_set = true;
    }

    // 1) fused prep: fp32->fp16 x + W planes, zero row sums
    prep_kernel<<<dim3(11264), 256, 0, stream>>>(x, Wq, Wk, Wv, xh, Wh3, sums);

    // 2) QKV (Q pre-scaled by 1/sqrt(D); V written transposed -> Vt)
    qkv_mfma_kernel<<<dim3(D / 128, (Bn * S) / 256, 3), 512, 147456, stream>>>(
        xh, Wh3, bq, bk, bv, Qh, Kh, Vt);

    // 3) attention: exp-scores 256x256 (+row sums) -> PV w/ normalize
    scores_exp_kernel<<<dim3(S / 256, S / 256, Bn), 512, 131072, stream>>>(
        Qh, Kh, P, sums);
    pv_mfma_kernel<<<dim3(D / 128, S / 256, Bn), 512, 147456, stream>>>(
        P, Vt, sums, out);
}

// Round 9
// 245.750 us; speedup vs baseline: 1.4825x; 1.0066x over previous
//
#include <hip/hip_runtime.h>
#include <math.h>

// ---------------------------------------------------------------------------
// SimpleSelfAttention  B=4 S=2048 D=1024  fp32
// Round 17: fuse the 3 QKV GEMMs into ONE block per (m0,n0): A (xh) staged
// and fragment-read ONCE for 3 B-planes -> DS/MFMA ratio 0.5 -> 0.33
// (MFMA-bound at last). Grid 256 = exactly 1 round. LDS 160KB 2-deep
// (A 256x64 + Bconcat 384x64), counted vmcnt(10), R16 2-barrier placement.
// scores keeps the 256x256 8-wave core (41% measured), pv keeps core3.
// ---------------------------------------------------------------------------

typedef _Float16 f16;
typedef _Float16 f16x8 __attribute__((ext_vector_type(8)));
typedef _Float16 f16x4 __attribute__((ext_vector_type(4)));
typedef float f32x4 __attribute__((ext_vector_type(4)));

__device__ __forceinline__ void glds16(const void* g, const void* l) {
    __builtin_amdgcn_global_load_lds(
        (const __attribute__((address_space(1))) void*)g,
        (__attribute__((address_space(3))) void*)l, 16, 0, 0);
}

#define VMCNT(n)  asm volatile("s_waitcnt vmcnt(" #n ")" ::: "memory")
#define LGKM(n)   asm volatile("s_waitcnt lgkmcnt(" #n ")" ::: "memory")
#define BARRIER() asm volatile("s_barrier" ::: "memory")
#define SCHEDB()  __builtin_amdgcn_sched_barrier(0)

// fused prep: fp32->fp16 for x (blocks [0,8192)), W planes (blocks [8192,11264)),
// zero sums (blocks [0,8))
__global__ __launch_bounds__(256) void prep_kernel(
    const float* __restrict__ x,
    const float* __restrict__ Wq, const float* __restrict__ Wk,
    const float* __restrict__ Wv,
    f16* __restrict__ xh, f16* __restrict__ Wh3, float* __restrict__ sums)
{
    const int bid = blockIdx.x, tid = threadIdx.x;
    if (bid < 8) {
        float4 z = {0.f, 0.f, 0.f, 0.f};
        ((float4*)sums)[bid * 256 + tid] = z;     // 8*256*4 = 8192 floats
    }
    if (bid < 8192) {
        const int i = bid * 256 + tid;
        float4 v = ((const float4*)x)[i];
        f16x4 h = { (f16)v.x, (f16)v.y, (f16)v.z, (f16)v.w };
        ((f16x4*)xh)[i] = h;
    } else {
        const int wid   = bid - 8192;             // 0..3071
        const int plane = wid >> 10;              // 0..2
        const int i     = (wid & 1023) * 256 + tid;
        const float* src = (plane == 0) ? Wq : (plane == 1) ? Wk : Wv;
        float4 v = ((const float4*)src)[i];
        f16x4 h = { (f16)v.x, (f16)v.y, (f16)v.z, (f16)v.w };
        ((f16x4*)(Wh3 + (size_t)plane * 1024 * 1024))[i] = h;
    }
}

// ---------------------------------------------------------------------------
// Fused QKV kernel: one block computes Q/K/V 256x128 tiles sharing the A
// stage/reads. 8 waves 4M x 2N (wave tile 64x64 per plane). BK=64, 2-deep,
// counted vmcnt(10). LDS: 2 x (A 256x64 = 32KB + B 384x64 = 48KB) = 160KB.
// XOR-swizzled 16B slots (slot s of row r holds k-chunk s ^ (r&7)).
// grid 256: bx = bid>>5 (n-tile), by = bid&31 (m-tile); XCD = bid%8 = by%8
// so each XCD touches only 4 distinct A panels (L2 locality).
// ---------------------------------------------------------------------------
__global__ __launch_bounds__(512, 2) void qkv_fused_kernel(
    const f16* __restrict__ xh, const f16* __restrict__ Wh3,
    const float* __restrict__ bq, const float* __restrict__ bk,
    const float* __restrict__ bv,
    f16* __restrict__ Qh, f16* __restrict__ Kh, f16* __restrict__ Vt)
{
    extern __shared__ __align__(16) f16 smem[];
    const int bx = blockIdx.x >> 5;     // 0..7  -> n0
    const int by = blockIdx.x & 31;     // 0..31 -> m0
    const int m0 = by * 256;
    const int n0 = bx * 128;

    const int tid  = threadIdx.x;
    const int lane = tid & 63;
    const int w    = tid >> 6;          // 0..7
    const int wr   = w >> 1;            // 0..3 : wave row (64 rows)
    const int wc   = w & 1;             // 0..1 : wave col (64 cols)
    const int lr   = lane & 15;
    const int kq   = lane >> 4;

    const int rl = lane >> 3;           // staging row within 8-row group
    const int ch = (lane & 7) ^ rl;     // source k-chunk for this slot

    // 32-bit staging offsets (base ptr stays in SGPR)
    unsigned oA[4];
    #pragma unroll
    for (int p = 0; p < 4; ++p)
        oA[p] = (unsigned)((m0 + p * 64 + w * 8 + rl) * 1024 + ch * 8);
    unsigned oB[6];
    #pragma unroll
    for (int p = 0; p < 6; ++p) {
        const int g  = w * 48 + p * 8;          // concat row base (mult of 8)
        const int pl = g >> 7;                  // plane 0..2
        const int rp = g & 127;                 // row in plane
        oB[p] = (unsigned)(pl * 1048576 + (n0 + rp + rl) * 1024 + ch * 8);
    }

    f16* sA0 = smem;                f16* sA1 = smem + 16384;
    f16* sB0 = smem + 32768;        f16* sB1 = smem + 32768 + 24576;

    #define STAGEF(kofs, dA, dB) do {                                         \
        _Pragma("unroll")                                                     \
        for (int p = 0; p < 4; ++p)                                           \
            glds16(xh + oA[p] + (kofs), (dA) + w * 512 + p * 4096);           \
        _Pragma("unroll")                                                     \
        for (int p = 0; p < 6; ++p)                                           \
            glds16(Wh3 + oB[p] + (kofs), (dB) + w * 3072 + p * 512);          \
    } while (0)

    f32x4 aQ[4][4], aK[4][4], aV[4][4];
    #pragma unroll
    for (int i = 0; i < 4; ++i)
        #pragma unroll
        for (int j = 0; j < 4; ++j) {
            aQ[i][j] = (f32x4){0.f, 0.f, 0.f, 0.f};
            aK[i][j] = (f32x4){0.f, 0.f, 0.f, 0.f};
            aV[i][j] = (f32x4){0.f, 0.f, 0.f, 0.f};
        }

    STAGEF(0, sA0, sB0);                // tile 0 (10 loads)
    f16* curA = sA0; f16* curB = sB0;
    f16* othA = sA1; f16* othB = sB1;

    for (int t = 0; t < 16; ++t) {
        if (t < 15) { STAGEF((t + 1) * 64, othA, othB); VMCNT(10); }
        else        { VMCNT(0); }
        BARRIER();                      // tile t collectively ready

        #pragma unroll
        for (int kk = 0; kk < 2; ++kk) {
            const int c = kk * 4 + kq;
            f16x8 a[4];
            #pragma unroll
            for (int i = 0; i < 4; ++i) {
                const int ra = wr * 64 + i * 16 + lr;
                a[i] = *(const f16x8*)&curA[ra * 64 + ((c ^ (ra & 7)) * 8)];
            }
            #define ZBLOCK(zi, ACC, ISLAST) do {                              \
                f16x8 b[4];                                                   \
                _Pragma("unroll")                                             \
                for (int j = 0; j < 4; ++j) {                                 \
                    const int rb = (zi) * 128 + wc * 64 + j * 16 + lr;        \
                    b[j] = *(const f16x8*)&curB[rb * 64 + ((c ^ (rb & 7)) * 8)]; \
                }                                                             \
                LGKM(0);                                                      \
                if (ISLAST) BARRIER();  /* all reads of cur retired */        \
                SCHEDB();                                                     \
                __builtin_amdgcn_s_setprio(1);                                \
                _Pragma("unroll")                                             \
                for (int i = 0; i < 4; ++i)                                   \
                    _Pragma("unroll")                                         \
                    for (int j = 0; j < 4; ++j)                               \
                        ACC[i][j] = __builtin_amdgcn_mfma_f32_16x16x32_f16(   \
                            a[i], b[j], ACC[i][j], 0, 0, 0);                  \
                __builtin_amdgcn_s_setprio(0);                                \
            } while (0)

            ZBLOCK(0, aQ, false);
            ZBLOCK(1, aK, false);
            ZBLOCK(2, aV, kk == 1);
            #undef ZBLOCK
        }

        f16* xp;
        xp = curA; curA = othA; othA = xp;
        xp = curB; curB = othB; othB = xp;
    }
    #undef STAGEF

    // ---- epilogue: Q (bias + 1/32 scale), K (bias), V transposed ----
    const int col  = lr;
    const int quad = kq;
    #pragma unroll
    for (int j = 0; j < 4; ++j) {
        const int gn = n0 + wc * 64 + j * 16 + col;
        const float bbq = bq[gn];
        const float bbk = bk[gn];
        #pragma unroll
        for (int i = 0; i < 4; ++i)
            #pragma unroll
            for (int r = 0; r < 4; ++r) {
                const int gm = m0 + wr * 64 + i * 16 + quad * 4 + r;
                Qh[(size_t)gm * 1024 + gn] = (f16)((aQ[i][j][r] + bbq) * 0.03125f);
                Kh[(size_t)gm * 1024 + gn] = (f16)(aK[i][j][r] + bbk);
            }
    }
    #pragma unroll
    for (int i = 0; i < 4; ++i) {
        const int gmb = m0 + wr * 64 + i * 16 + quad * 4;   // r=0 base (s)
        const int bb_ = gmb >> 11;
        const int s   = gmb & 2047;
        f16* vtb = Vt + (size_t)bb_ * 1024 * 2048;
        #pragma unroll
        for (int j = 0; j < 4; ++j) {
            const int gn = n0 + wc * 64 + j * 16 + col;
            const float bbv = bv[gn];
            f16x4 v = { (f16)(aV[i][j][0] + bbv), (f16)(aV[i][j][1] + bbv),
                        (f16)(aV[i][j][2] + bbv), (f16)(aV[i][j][3] + bbv) };
            *(f16x4*)&vtb[(size_t)gn * 2048 + s] = v;
        }
    }
}

// ---------------------------------------------------------------------------
// 256x128 NT fp16 MFMA core, BK=64, 3-deep LDS pipeline, counted vmcnt.
// (pv). 2 barriers/K-tile. LDS 144 KiB, XOR-swizzled.
// ---------------------------------------------------------------------------
#define ABUF 16384      // f16 per A buffer (256*64)
#define BBUF 8192       // f16 per B buffer (128*64)
#define BOFF 49152      // f16 offset of B buffers (3*ABUF)

__device__ __forceinline__ void mfma_core3(
    const f16* A, int lda,
    const f16* B, int ldb,
    int K, int m0, int n0, f16* sm, f32x4 acc[4][4])
{
    const int tid  = threadIdx.x;
    const int lane = tid & 63;
    const int w    = tid >> 6;          // 0..7
    const int wr   = w >> 1;
    const int wc   = w & 1;
    const int lr   = lane & 15;
    const int kq   = lane >> 4;

    const int rl = lane >> 3;
    const int ch = (lane & 7) ^ rl;

    const f16* gA[4];
    #pragma unroll
    for (int p = 0; p < 4; ++p)
        gA[p] = A + (size_t)(m0 + p * 64 + w * 8 + rl) * lda + ch * 8;
    const f16* gB[2];
    #pragma unroll
    for (int p = 0; p < 2; ++p)
        gB[p] = B + (size_t)(n0 + p * 64 + w * 8 + rl) * ldb + ch * 8;

    const int NT = K >> 6;

    f16* sA0 = sm;             f16* sB0 = sm + BOFF;
    f16* sA1 = sm + ABUF;      f16* sB1 = sm + BOFF + BBUF;
    f16* sA2 = sm + 2 * ABUF;  f16* sB2 = sm + BOFF + 2 * BBUF;

    #define STAGE(kofs, dA, dB) do {                                          \
        _Pragma("unroll")                                                     \
        for (int p = 0; p < 4; ++p)                                           \
            glds16(gA[p] + (kofs), (dA) + w * 512 + p * 4096);                \
        _Pragma("unroll")                                                     \
        for (int p = 0; p < 2; ++p)                                           \
            glds16(gB[p] + (kofs), (dB) + w * 512 + p * 4096);                \
    } while (0)

    STAGE(0,  sA0, sB0);
    STAGE(64, sA1, sB1);

    int kst = 128;
    f16* curA = sA0; f16* curB = sB0;
    f16* nxtA = sA1; f16* nxtB = sB1;
    f16* farA = sA2; f16* farB = sB2;

    for (int t = 0; t < NT; ++t) {
        if (t + 2 < NT) {
            STAGE(kst, farA, farB);
            kst += 64;
            VMCNT(12);
        } else if (t + 1 < NT) {
            VMCNT(6);
        } else {
            VMCNT(0);
        }
        BARRIER();

        // kk = 0
        {
            f16x8 a[4], b[4];
            #pragma unroll
            for (int i = 0; i < 4; ++i) {
                const int ra = wr * 64 + i * 16 + lr;
                a[i] = *(const f16x8*)&curA[ra * 64 + ((kq ^ (ra & 7)) * 8)];
            }
            #pragma unroll
            for (int j = 0; j < 4; ++j) {
                const int rb = wc * 64 + j * 16 + lr;
                b[j] = *(const f16x8*)&curB[rb * 64 + ((kq ^ (rb & 7)) * 8)];
            }
            LGKM(0);
            SCHEDB();
            __builtin_amdgcn_s_setprio(1);
            #pragma unroll
            for (int i = 0; i < 4; ++i)
                #pragma unroll
                for (int j = 0; j < 4; ++j)
                    acc[i][j] = __builtin_amdgcn_mfma_f32_16x16x32_f16(a[i], b[j], acc[i][j], 0, 0, 0);
            __builtin_amdgcn_s_setprio(0);
        }
        // kk = 1 : barrier after reads retire, before MFMAs
        {
            f16x8 a[4], b[4];
            const int c = 4 + kq;
            #pragma unroll
            for (int i = 0; i < 4; ++i) {
                const int ra = wr * 64 + i * 16 + lr;
                a[i] = *(const f16x8*)&curA[ra * 64 + ((c ^ (ra & 7)) * 8)];
            }
            #pragma unroll
            for (int j = 0; j < 4; ++j) {
                const int rb = wc * 64 + j * 16 + lr;
                b[j] = *(const f16x8*)&curB[rb * 64 + ((c ^ (rb & 7)) * 8)];
            }
            LGKM(0);
            BARRIER();
            SCHEDB();
            __builtin_amdgcn_s_setprio(1);
            #pragma unroll
            for (int i = 0; i < 4; ++i)
                #pragma unroll
                for (int j = 0; j < 4; ++j)
                    acc[i][j] = __builtin_amdgcn_mfma_f32_16x16x32_f16(a[i], b[j], acc[i][j], 0, 0, 0);
            __builtin_amdgcn_s_setprio(0);
        }

        f16* tA = curA; f16* tB = curB;
        curA = nxtA; curB = nxtB;
        nxtA = farA; nxtB = farB;
        farA = tA;   farB = tB;
    }
    #undef STAGE
}

// ---------------------------------------------------------------------------
// 256x256 NT fp16 MFMA core (scores): 8 waves 2M x 4N, wave tile 128x64,
// BK=64, 2-deep double buffer, counted vmcnt(8). LDS 128 KiB.
// ---------------------------------------------------------------------------
__device__ __forceinline__ void mfma_core8w(
    const f16* A, int lda,
    const f16* B, int ldb,
    int K, int m0, int n0, f16* sm, f32x4 (&acc)[8][4])
{
    const int tid  = threadIdx.x;
    const int lane = tid & 63;
    const int w    = tid >> 6;
    const int wr   = w >> 2;            // 0..1 : 128-row half
    const int wn   = w & 3;             // 0..3 : 64-col quarter
    const int lr   = lane & 15;
    const int kq   = lane >> 4;

    const int rl = lane >> 3;
    const int ch = (lane & 7) ^ rl;

    const f16* gA[4];
    #pragma unroll
    for (int p = 0; p < 4; ++p)
        gA[p] = A + (size_t)(m0 + p * 64 + w * 8 + rl) * lda + ch * 8;
    const f16* gB[4];
    #pragma unroll
    for (int p = 0; p < 4; ++p)
        gB[p] = B + (size_t)(n0 + p * 64 + w * 8 + rl) * ldb + ch * 8;

    const int NT = K >> 6;

    f16* sA0 = sm;              f16* sA1 = sm + 16384;
    f16* sB0 = sm + 32768;      f16* sB1 = sm + 49152;

    #define STAGE8(kofs, dA, dB) do {                                         \
        _Pragma("unroll")                                                     \
        for (int p = 0; p < 4; ++p)                                           \
            glds16(gA[p] + (kofs), (dA) + w * 512 + p * 4096);                \
        _Pragma("unroll")                                                     \
        for (int p = 0; p < 4; ++p)                                           \
            glds16(gB[p] + (kofs), (dB) + w * 512 + p * 4096);                \
    } while (0)

    STAGE8(0, sA0, sB0);

    f16* curA = sA0; f16* curB = sB0;
    f16* othA = sA1; f16* othB = sB1;

    for (int t = 0; t < NT; ++t) {
        if (t + 1 < NT) {
            STAGE8((t + 1) * 64, othA, othB);
            VMCNT(8);
        } else {
            VMCNT(0);
        }
        BARRIER();

        #pragma unroll
        for (int kk = 0; kk < 2; ++kk) {
            f16x8 a[8], b[4];
            const int c = kk * 4 + kq;
            #pragma unroll
            for (int i = 0; i < 8; ++i) {
                const int ra = wr * 128 + i * 16 + lr;
                a[i] = *(const f16x8*)&curA[ra * 64 + ((c ^ (ra & 7)) * 8)];
            }
            #pragma unroll
            for (int j = 0; j < 4; ++j) {
                const int rb = wn * 64 + j * 16 + lr;
                b[j] = *(const f16x8*)&curB[rb * 64 + ((c ^ (rb & 7)) * 8)];
            }
            LGKM(0);
            if (kk == 1) BARRIER();
            SCHEDB();
            __builtin_amdgcn_s_setprio(1);
            #pragma unroll
            for (int i = 0; i < 8; ++i)
                #pragma unroll
                for (int j = 0; j < 4; ++j)
                    acc[i][j] = __builtin_amdgcn_mfma_f32_16x16x32_f16(a[i], b[j], acc[i][j], 0, 0, 0);
            __builtin_amdgcn_s_setprio(0);
        }

        f16* x;
        x = curA; curA = othA; othA = x;
        x = curB; curB = othB; othB = x;
    }
    #undef STAGE8
}

// grid (8, 8, 4): 256x256 tiles, exactly 1 round. P = exp(QK^T) fp16,
// row sums accumulated into sums[b*S + row] via atomicAdd.
__global__ __launch_bounds__(512, 2) void scores_exp_kernel(
    const f16* __restrict__ Qh, const f16* __restrict__ Kh,
    f16* __restrict__ P, float* __restrict__ sums)
{
    extern __shared__ __align__(16) f16 smem[];
    const int b  = blockIdx.z;
    const int m0 = blockIdx.y * 256;
    const int n0 = blockIdx.x * 256;

    f32x4 acc[8][4];
    #pragma unroll
    for (int i = 0; i < 8; ++i)
        #pragma unroll
        for (int j = 0; j < 4; ++j) acc[i][j] = (f32x4){0.f, 0.f, 0.f, 0.f};

    const size_t ao = (size_t)b * 2048 * 1024;
    mfma_core8w(Qh + ao, 1024, Kh + ao, 1024, 1024, m0, n0, smem, acc);

    const int lane = threadIdx.x & 63;
    const int w    = threadIdx.x >> 6;
    const int wr = w >> 2, wn = w & 3;
    const int col  = lane & 15;
    const int quad = lane >> 4;
    f16* C = P + (size_t)b * 2048 * 2048;

    float rp[8][4];
    #pragma unroll
    for (int i = 0; i < 8; ++i)
        #pragma unroll
        for (int r = 0; r < 4; ++r) rp[i][r] = 0.0f;

    #pragma unroll
    for (int i = 0; i < 8; ++i)
        #pragma unroll
        for (int r = 0; r < 4; ++r) {
            const int gm = m0 + wr * 128 + i * 16 + quad * 4 + r;
            #pragma unroll
            for (int j = 0; j < 4; ++j) {
                const int gn = n0 + wn * 64 + j * 16 + col;
                const f16 p = (f16)__expf(acc[i][j][r]);
                C[(size_t)gm * 2048 + gn] = p;
                rp[i][r] += (float)p;   // sum what pv will actually read
            }
        }

    #pragma unroll
    for (int i = 0; i < 8; ++i)
        #pragma unroll
        for (int r = 0; r < 4; ++r) {
            float v = rp[i][r];
            v += __shfl_xor(v, 1);
            v += __shfl_xor(v, 2);
            v += __shfl_xor(v, 4);
            v += __shfl_xor(v, 8);
            rp[i][r] = v;
        }
    if (col == 0) {
        #pragma unroll
        for (int i = 0; i < 8; ++i)
            #pragma unroll
            for (int r = 0; r < 4; ++r) {
                const int row = m0 + wr * 128 + i * 16 + quad * 4 + r;
                atomicAdd(&sums[b * 2048 + row], rp[i][r]);
            }
    }
}

// grid (8, 8, 4); out[r] = (P[r] @ Vt^T) / sums[r]
__global__ __launch_bounds__(512) void pv_mfma_kernel(
    const f16* __restrict__ P, const f16* __restrict__ Vt,
    const float* __restrict__ sums, float* __restrict__ out)
{
    extern __shared__ __align__(16) f16 smem[];
    const int b  = blockIdx.z;
    const int m0 = blockIdx.y * 256;
    const int n0 = blockIdx.x * 128;

    f32x4 acc[4][4];
    #pragma unroll
    for (int i = 0; i < 4; ++i)
        #pragma unroll
        for (int j = 0; j < 4; ++j) acc[i][j] = (f32x4){0.f, 0.f, 0.f, 0.f};

    const size_t ao = (size_t)b * 2048 * 2048;
    const size_t bo = (size_t)b * 1024 * 2048;
    mfma_core3(P + ao, 2048, Vt + bo, 2048, 2048, m0, n0, smem, acc);

    const int lane = threadIdx.x & 63;
    const int w    = threadIdx.x >> 6;
    const int wm = (w >> 1) * 64;
    const int wn = (w & 1) * 64;
    const int col  = lane & 15;
    const int quad = lane >> 4;
    float* C = out + (size_t)b * 2048 * 1024;

    #pragma unroll
    for (int i = 0; i < 4; ++i)
        #pragma unroll
        for (int r = 0; r < 4; ++r) {
            const int rl = m0 + wm + i * 16 + quad * 4 + r;
            const float inv = 1.0f / sums[b * 2048 + rl];
            #pragma unroll
            for (int j = 0; j < 4; ++j) {
                const int gn = n0 + wn + j * 16 + col;
                C[(size_t)rl * 1024 + gn] = acc[i][j][r] * inv;
            }
        }
}

// ===========================================================================
extern "C" void kernel_launch(void* const* d_in, const int* in_sizes, int n_in,
                              void* d_out, int out_size, void* d_ws, size_t ws_size,
                              hipStream_t stream)
{
    (void)in_sizes; (void)n_in; (void)out_size; (void)ws_size;
    const int Bn = 4, S = 2048, D = 1024;
    const float* x  = (const float*)d_in[0];
    const float* Wq = (const float*)d_in[1];
    const float* bq = (const float*)d_in[2];
    const float* Wk = (const float*)d_in[3];
    const float* bk = (const float*)d_in[4];
    const float* Wv = (const float*)d_in[5];
    const float* bv = (const float*)d_in[6];
    float* out = (float*)d_out;

    const size_t MB = 1024 * 1024;
    char* w = (char*)d_ws;
    // [0..16)  xh   — dead after qkv   \
    // [16..22) Wh3  — dead after qkv    > P (32 MiB) aliases [0..38)
    // [22..38) (free)                  /
    // [38..54) Qh   [54..70) Kh   [70..86) Vt   [86..87) sums
    f16*   xh   = (f16*)(w + 0 * MB);
    f16*   Wh3  = (f16*)(w + 16 * MB);
    f16*   Qh   = (f16*)(w + 38 * MB);
    f16*   Kh   = (f16*)(w + 54 * MB);
    f16*   Vt   = (f16*)(w + 70 * MB);
    float* sums = (float*)(w + 86 * MB);
    f16*   P    = (f16*)(w + 0 * MB);

    static bool attr_set = false;
    if (!attr_set) {
        (void)hipFuncSetAttribute(reinterpret_cast<const void*>(qkv_fused_kernel),
                            hipFuncAttributeMaxDynamicSharedMemorySize, 163840);
        (void)hipFuncSetAttribute(reinterpret_cast<const void*>(scores_exp_kernel),
                            hipFuncAttributeMaxDynamicSharedMemorySize, 131072);
        (void)hipFuncSetAttribute(reinterpret_cast<const void*>(pv_mfma_kernel),
                            hipFuncAttributeMaxDynamicSharedMemorySize, 147456);
        attr_set = true;
    }

    // 1) fused prep: fp32->fp16 x + W planes, zero row sums
    prep_kernel<<<dim3(11264), 256, 0, stream>>>(x, Wq, Wk, Wv, xh, Wh3, sums);

    // 2) QKV fused: one block per (m,n) computes Q, K, V^T tiles
    qkv_fused_kernel<<<dim3(256), 512, 163840, stream>>>(
        xh, Wh3, bq, bk, bv, Qh, Kh, Vt);

    // 3) attention: exp-scores 256x256 (+row sums) -> PV w/ normalize
    scores_exp_kernel<<<dim3(S / 256, S / 256, Bn), 512, 131072, stream>>>(
        Qh, Kh, P, sums);
    pv_mfma_kernel<<<dim3(D / 128, S / 256, Bn), 512, 147456, stream>>>(
        P, Vt, sums, out);
}